// Round 1
// baseline (708.669 us; speedup 1.0000x reference)
//
#include <hip/hip_runtime.h>
#include <stdint.h>

#define N_NODES 8192
#define IN_F    512
#define OUT_F   256
#define ALPHA   0.2f

typedef __attribute__((ext_vector_type(8))) short bf16x8;
typedef __attribute__((ext_vector_type(4))) float f32x4;

__device__ __forceinline__ uint32_t f32_to_bf16(float f) {
    union { float f; uint32_t u; } v; v.f = f;
    uint32_t u = v.u;
    return (u + 0x7fffu + ((u >> 16) & 1u)) >> 16;   // RNE
}

// ---------------------------------------------------------------------------
// K1: Wh = h @ W^T   (fp32, [8192,512] x [256,512]^T -> [8192,256])
//     + fused s_src/s_dst partial dot products via atomicAdd
// grid (4 colblocks, 64 rowblocks), block 128. Tile 128x64, BK=32, thread 8x8.
// ---------------------------------------------------------------------------
__global__ __launch_bounds__(128) void k1_gemm_wh(
    const float* __restrict__ h, const float* __restrict__ W,
    const float* __restrict__ a_vec, float* __restrict__ wh,
    float* __restrict__ s_src, float* __restrict__ s_dst)
{
    const int cb = blockIdx.x;            // 0..3
    const int rb = blockIdx.y;            // 0..63
    const int i0 = rb * 128, n0 = cb * 64;
    const int t  = threadIdx.x;
    const int tm = t >> 3, tn = t & 7;    // 16 x 8 threads -> 8x8 each

    __shared__ float As[32][132];         // K-major [kk][row], pad vs conflicts
    __shared__ float Bs[32][68];          // [kk][col]

    float acc[8][8];
    #pragma unroll
    for (int i = 0; i < 8; i++)
        #pragma unroll
        for (int j = 0; j < 8; j++) acc[i][j] = 0.f;

    for (int k0 = 0; k0 < IN_F; k0 += 32) {
        __syncthreads();
        #pragma unroll
        for (int q = 0; q < 8; q++) {                 // A: 128x32 = 1024 float4/128thr
            int u = q * 128 + t;
            int row = u >> 3;
            int ks  = (u & 7) * 4;
            float4 v = *(const float4*)&h[(size_t)(i0 + row) * IN_F + k0 + ks];
            As[ks + 0][row] = v.x; As[ks + 1][row] = v.y;
            As[ks + 2][row] = v.z; As[ks + 3][row] = v.w;
        }
        #pragma unroll
        for (int q = 0; q < 4; q++) {                 // B: 64x32 = 512 float4/128thr
            int u = q * 128 + t;
            int row = u >> 3;
            int ks  = (u & 7) * 4;
            float4 v = *(const float4*)&W[(size_t)(n0 + row) * IN_F + k0 + ks];
            Bs[ks + 0][row] = v.x; Bs[ks + 1][row] = v.y;
            Bs[ks + 2][row] = v.z; Bs[ks + 3][row] = v.w;
        }
        __syncthreads();
        #pragma unroll
        for (int kk = 0; kk < 32; kk++) {
            float a[8], b[8];
            *(float4*)&a[0] = *(const float4*)&As[kk][tm * 8];
            *(float4*)&a[4] = *(const float4*)&As[kk][tm * 8 + 4];
            *(float4*)&b[0] = *(const float4*)&Bs[kk][tn * 8];
            *(float4*)&b[4] = *(const float4*)&Bs[kk][tn * 8 + 4];
            #pragma unroll
            for (int i = 0; i < 8; i++)
                #pragma unroll
                for (int j = 0; j < 8; j++) acc[i][j] = fmaf(a[i], b[j], acc[i][j]);
        }
    }

    float a1[8], a2[8];
    #pragma unroll
    for (int j = 0; j < 8; j++) {
        a1[j] = a_vec[n0 + tn * 8 + j];
        a2[j] = a_vec[OUT_F + n0 + tn * 8 + j];
    }
    #pragma unroll
    for (int i = 0; i < 8; i++) {
        int gr = i0 + tm * 8 + i;
        *(float4*)&wh[(size_t)gr * OUT_F + n0 + tn * 8]     = *(float4*)&acc[i][0];
        *(float4*)&wh[(size_t)gr * OUT_F + n0 + tn * 8 + 4] = *(float4*)&acc[i][4];
        float v1 = 0.f, v2 = 0.f;
        #pragma unroll
        for (int j = 0; j < 8; j++) { v1 = fmaf(acc[i][j], a1[j], v1); v2 = fmaf(acc[i][j], a2[j], v2); }
        v1 += __shfl_xor(v1, 4, 64); v2 += __shfl_xor(v2, 4, 64);
        v1 += __shfl_xor(v1, 2, 64); v2 += __shfl_xor(v2, 2, 64);
        v1 += __shfl_xor(v1, 1, 64); v2 += __shfl_xor(v2, 1, 64);
        if (tn == 0) { atomicAdd(&s_src[gr], v1); atomicAdd(&s_dst[gr], v2); }
    }
}

// ---------------------------------------------------------------------------
// K1c: repack Wh fp32 -> WhF bf16 in MFMA-B-fragment-major layout.
// WhF chunk index = (k/32)*16 + nt ; each chunk = 64 lanes x 8 bf16 (1 KB):
//   B[k][n] with n = nt*16 + (lane&15), k = ks*32 + (lane>>4)*8 + jj
// grid 1024, block 256 (4 chunks / block).
// ---------------------------------------------------------------------------
__global__ __launch_bounds__(256) void k1c_whf(
    const float* __restrict__ wh, uint16_t* __restrict__ whf)
{
    const int c    = blockIdx.x * 4 + (threadIdx.x >> 6);  // 0..4095
    const int lane = threadIdx.x & 63;
    const int ks   = c >> 4, nt = c & 15;
    const int rb   = ks * 32 + (lane >> 4) * 8;
    const int col  = nt * 16 + (lane & 15);
    uint32_t v[8];
    #pragma unroll
    for (int jj = 0; jj < 8; jj++)
        v[jj] = f32_to_bf16(wh[(size_t)(rb + jj) * OUT_F + col]);
    uint4 pk;
    pk.x = v[0] | (v[1] << 16);
    pk.y = v[2] | (v[3] << 16);
    pk.z = v[4] | (v[5] << 16);
    pk.w = v[6] | (v[7] << 16);
    *(uint4*)(whf + (size_t)c * 512 + lane * 8) = pk;
}

// ---------------------------------------------------------------------------
// K2: adjacency -> bitmask + softmax denominators l[i] (no max-subtraction:
// scores bounded ~|12| so exp never overflows; exp(-9e15)=0 matches ref).
// grid 8192 (1 row / block), block 256.
// ---------------------------------------------------------------------------
__global__ __launch_bounds__(256) void k2_mask_l(
    const float* __restrict__ adj, const float* __restrict__ s_src,
    const float* __restrict__ s_dst, uint64_t* __restrict__ mask,
    float* __restrict__ l_out)
{
    const int i = blockIdx.x;
    const int t = threadIdx.x;
    const int w = t >> 6, lane = t & 63;
    const float si = s_src[i];
    const float* row = adj + (size_t)i * N_NODES;
    float acc = 0.f;
    #pragma unroll 4
    for (int it = 0; it < 32; it++) {
        int j = it * 256 + t;
        float a = row[j];
        uint64_t m = __ballot(a > 0.f);
        if (lane == 0) mask[(size_t)i * 128 + it * 4 + w] = m;
        float x = si + s_dst[j];
        float e = fmaxf(x, ALPHA * x);          // leaky_relu, alpha>0
        float p = __expf(e);
        acc += (a > 0.f) ? p : 0.f;
    }
    #pragma unroll
    for (int off = 32; off >= 1; off >>= 1) acc += __shfl_xor(acc, off, 64);
    __shared__ float red[4];
    if (lane == 0) red[w] = acc;
    __syncthreads();
    if (t == 0) l_out[i] = (red[0] + red[1]) + (red[2] + red[3]);
}

// ---------------------------------------------------------------------------
// K3: fused attention-write + (attention @ Wh) bf16 MFMA GEMM.
// grid (128 rowblocks, 4 j-chunks), block 256 (4 waves).
// Block: 64 rows x 2048 j. Per iter (BK=64): recompute att from s_src/s_dst+
// bitmask directly in A-fragment slot order (8 consecutive j per slot), write
// fp32 att to d_out, bf16 to LDS; stage WhF tile (frag-major, lane-contiguous,
// conflict-free); MFMA 16x16x32, wave-tile 32x128, acc 2x8x4 fp32.
// Split-K over 4 j-chunks -> partial h_prime buffers.
// ---------------------------------------------------------------------------
__global__ __launch_bounds__(256) void k3_att_gemm(
    const uint64_t* __restrict__ mask, const float* __restrict__ s_src,
    const float* __restrict__ s_dst, const float* __restrict__ l_in,
    const uint16_t* __restrict__ whf, float* __restrict__ att_out,
    float* __restrict__ partial)
{
    const int rb = blockIdx.x, jc = blockIdx.y;
    const int i0 = rb * 64;
    const int jbase = jc * 2048;
    const int t = threadIdx.x;
    const int w = t >> 6, lane = t & 63;

    __shared__ uint16_t whf_lds[32 * 512];   // 32 KB: 2 ksteps x 16 ntiles
    __shared__ uint16_t attf_lds[8 * 512];   // 8 KB: 2 ksteps x 4 mtiles
    __shared__ uint64_t mw[2][64];
    __shared__ float    sd[2][64];
    __shared__ float    ssrc[64], invl[64];

    if (t < 64) {
        ssrc[t] = s_src[i0 + t];
        invl[t] = 1.0f / l_in[i0 + t];
        mw[0][t] = mask[(size_t)(i0 + t) * 128 + (jbase >> 6)];
        sd[0][t] = s_dst[jbase + t];
    }

    f32x4 acc[2][8];
    #pragma unroll
    for (int a = 0; a < 2; a++)
        #pragma unroll
        for (int b = 0; b < 8; b++) acc[a][b] = (f32x4){0.f, 0.f, 0.f, 0.f};

    const int mh = w & 1;    // row half (rows 32*mh..)
    const int nh = w >> 1;   // col half (cols 128*nh..)

    int cur = 0;
    for (int it = 0; it < 32; it++) {
        const int j0 = jbase + it * 64;
        __syncthreads();   // buf[cur] ready; prev MFMA done with LDS

        // stage WhF tile: 32 KB contiguous, coalesced
        const uint16_t* src = whf + (size_t)(j0 >> 5) * 8192;
        #pragma unroll
        for (int q = 0; q < 8; q++) {
            int u = q * 256 + t;
            *(uint4*)(whf_lds + u * 8) = *(const uint4*)(src + u * 8);
        }

        // att fragment pass: 2 slots/thread, each = (row m, 8 consecutive j)
        #pragma unroll
        for (int q = 0; q < 2; q++) {
            int s    = q * 256 + t;               // 0..511
            int ks   = s >> 8;                    // 0..1
            int mt   = (s >> 6) & 3;
            int ln   = s & 63;
            int m    = mt * 16 + (ln & 15);
            int kofs = ks * 32 + (ln >> 4) * 8;   // 0..56
            uint64_t mwv = mw[cur][m];
            float sim = ssrc[m], il = invl[m];
            float p[8];
            #pragma unroll
            for (int jj = 0; jj < 8; jj++) {
                float x  = sim + sd[cur][kofs + jj];
                float e  = fmaxf(x, ALPHA * x);
                float pe = __expf(e) * il;
                p[jj] = ((mwv >> (kofs + jj)) & 1ull) ? pe : 0.f;
            }
            float* go = att_out + (size_t)(i0 + m) * N_NODES + j0 + kofs;
            *(float4*)go       = *(float4*)&p[0];
            *(float4*)(go + 4) = *(float4*)&p[4];
            uint4 pk;
            pk.x = f32_to_bf16(p[0]) | (f32_to_bf16(p[1]) << 16);
            pk.y = f32_to_bf16(p[2]) | (f32_to_bf16(p[3]) << 16);
            pk.z = f32_to_bf16(p[4]) | (f32_to_bf16(p[5]) << 16);
            pk.w = f32_to_bf16(p[6]) | (f32_to_bf16(p[7]) << 16);
            *(uint4*)(attf_lds + (size_t)(ks * 4 + mt) * 512 + ln * 8) = pk;
        }

        // preload next iter's maskwords + s_dst block
        if (it < 31 && t < 64) {
            int jn = j0 + 64;
            mw[cur ^ 1][t] = mask[(size_t)(i0 + t) * 128 + (jn >> 6)];
            sd[cur ^ 1][t] = s_dst[jn + t];
        }
        __syncthreads();   // whf_lds + attf_lds ready

        #pragma unroll
        for (int ks = 0; ks < 2; ks++) {
            bf16x8 af[2];
            #pragma unroll
            for (int mi = 0; mi < 2; mi++) {
                int mt = mh * 2 + mi;
                af[mi] = *(const bf16x8*)(attf_lds + (size_t)(ks * 4 + mt) * 512 + lane * 8);
            }
            #pragma unroll
            for (int nl = 0; nl < 8; nl++) {
                int nt = nh * 8 + nl;
                bf16x8 bfr = *(const bf16x8*)(whf_lds + (size_t)(ks * 16 + nt) * 512 + lane * 8);
                acc[0][nl] = __builtin_amdgcn_mfma_f32_16x16x32_bf16(af[0], bfr, acc[0][nl], 0, 0, 0);
                acc[1][nl] = __builtin_amdgcn_mfma_f32_16x16x32_bf16(af[1], bfr, acc[1][nl], 0, 0, 0);
            }
        }
        cur ^= 1;
    }

    // epilogue: partial[jc][row][col]; C/D: col=lane&15, row=(lane>>4)*4+reg
    float* pbase = partial + (size_t)jc * ((size_t)N_NODES * OUT_F);
    #pragma unroll
    for (int mi = 0; mi < 2; mi++) {
        int gr0 = i0 + (mh * 2 + mi) * 16 + (lane >> 4) * 4;
        #pragma unroll
        for (int nl = 0; nl < 8; nl++) {
            int gc = nh * 128 + nl * 16 + (lane & 15);
            #pragma unroll
            for (int r = 0; r < 4; r++)
                pbase[(size_t)(gr0 + r) * OUT_F + gc] = acc[mi][nl][r];
        }
    }
}

// ---------------------------------------------------------------------------
// K4: h_prime = sum of 4 split-K partials
// ---------------------------------------------------------------------------
__global__ __launch_bounds__(256) void k4_reduce(
    const float* __restrict__ partial, float* __restrict__ hp)
{
    const size_t S = (size_t)N_NODES * OUT_F;
    int idx = (blockIdx.x * 256 + threadIdx.x) * 4;
    float4 a = *(const float4*)(partial + idx);
    float4 b = *(const float4*)(partial + S + idx);
    float4 c = *(const float4*)(partial + 2 * S + idx);
    float4 d = *(const float4*)(partial + 3 * S + idx);
    float4 o;
    o.x = (a.x + b.x) + (c.x + d.x);
    o.y = (a.y + b.y) + (c.y + d.y);
    o.z = (a.z + b.z) + (c.z + d.z);
    o.w = (a.w + b.w) + (c.w + d.w);
    *(float4*)(hp + idx) = o;
}

extern "C" void kernel_launch(void* const* d_in, const int* in_sizes, int n_in,
                              void* d_out, int out_size, void* d_ws, size_t ws_size,
                              hipStream_t stream) {
    (void)in_sizes; (void)n_in; (void)out_size; (void)ws_size;
    const float* h     = (const float*)d_in[0];
    const float* adj   = (const float*)d_in[1];
    const float* W     = (const float*)d_in[2];
    const float* a_vec = (const float*)d_in[3];

    char* ws = (char*)d_ws;
    uint16_t* whf  = (uint16_t*)(ws);                         // 4 MB frag-major bf16
    float* wh      = (float*)(ws + (size_t)(4u << 20));       // 8 MB
    float* s_src   = (float*)(ws + (size_t)(12u << 20));      // 32 KB
    float* s_dst   = (float*)(ws + (size_t)(12u << 20) + 32768);
    float* l_buf   = (float*)(ws + (size_t)(12u << 20) + 65536);
    uint64_t* mask = (uint64_t*)(ws + (size_t)(16u << 20));   // 8 MB
    float* partial = (float*)(ws + (size_t)(24u << 20));      // 32 MB

    float* hp  = (float*)d_out;
    float* att = hp + (size_t)N_NODES * OUT_F;

    hipMemsetAsync(s_src, 0, 65536, stream);  // zero s_src+s_dst for atomics
    k1_gemm_wh<<<dim3(4, 64), 128, 0, stream>>>(h, W, a_vec, wh, s_src, s_dst);
    k1c_whf<<<1024, 256, 0, stream>>>(wh, whf);
    k2_mask_l<<<8192, 256, 0, stream>>>(adj, s_src, s_dst, mask, l_buf);
    k3_att_gemm<<<dim3(128, 4), 256, 0, stream>>>(mask, s_src, s_dst, l_buf, whf, att, partial);
    k4_reduce<<<2048, 256, 0, stream>>>(partial, hp);
}

// Round 2
// 640.436 us; speedup vs baseline: 1.1065x; 1.1065x over previous
//
#include <hip/hip_runtime.h>
#include <stdint.h>

#define N_NODES 8192
#define IN_F    512
#define OUT_F   256
#define ALPHA   0.2f

typedef __attribute__((ext_vector_type(8))) short bf16x8;
typedef __attribute__((ext_vector_type(4))) float f32x4;

__device__ __forceinline__ uint32_t f32_to_bf16(float f) {
    union { float f; uint32_t u; } v; v.f = f;
    uint32_t u = v.u;
    return (u + 0x7fffu + ((u >> 16) & 1u)) >> 16;   // RNE
}

// async global->LDS, 16B per lane; LDS dest = uniform base + lane*16
__device__ __forceinline__ void async_copy16(const void* g, void* l) {
    __builtin_amdgcn_global_load_lds(
        (const __attribute__((address_space(1))) uint32_t*)g,
        (__attribute__((address_space(3))) uint32_t*)l, 16, 0, 0);
}

// ---------------------------------------------------------------------------
// K0: w1 = W^T a1, w2 = W^T a2  (w12[0:512]=w1, w12[512:1024]=w2)
// grid 32 blocks x 256 thr; block b covers W rows [8b, 8b+8); atomicAdd.
// ---------------------------------------------------------------------------
__global__ __launch_bounds__(256) void k0_wvec(
    const float* __restrict__ W, const float* __restrict__ a_vec,
    float* __restrict__ w12)
{
    const int t  = threadIdx.x;
    const int nb = blockIdx.x * 8;
    float a1lo = 0.f, a1hi = 0.f, a2lo = 0.f, a2hi = 0.f;
    #pragma unroll
    for (int q = 0; q < 8; q++) {
        int n = nb + q;
        float lo = W[(size_t)n * IN_F + t];
        float hi = W[(size_t)n * IN_F + t + 256];
        float a1 = a_vec[n], a2 = a_vec[OUT_F + n];
        a1lo = fmaf(lo, a1, a1lo); a1hi = fmaf(hi, a1, a1hi);
        a2lo = fmaf(lo, a2, a2lo); a2hi = fmaf(hi, a2, a2hi);
    }
    atomicAdd(&w12[t], a1lo);       atomicAdd(&w12[t + 256], a1hi);
    atomicAdd(&w12[512 + t], a2lo); atomicAdd(&w12[512 + t + 256], a2hi);
}

// ---------------------------------------------------------------------------
// Ks: s_src[i] = h[i] . w1 ; s_dst[i] = h[i] . w2   (1 wave per row)
// ---------------------------------------------------------------------------
__global__ __launch_bounds__(256) void ks_svec(
    const float* __restrict__ h, const float* __restrict__ w12,
    float* __restrict__ s_src, float* __restrict__ s_dst)
{
    __shared__ float sw[1024];
    const int t = threadIdx.x;
    #pragma unroll
    for (int q = 0; q < 4; q++) sw[q * 256 + t] = w12[q * 256 + t];
    __syncthreads();
    const int w = t >> 6, ln = t & 63;
    const int i = blockIdx.x * 4 + w;
    const float* hr = h + (size_t)i * IN_F + ln * 8;
    float4 h0 = *(const float4*)hr;
    float4 h1 = *(const float4*)(hr + 4);
    const float* w1 = sw + ln * 8;
    const float* w2 = sw + 512 + ln * 8;
    float v1 = h0.x*w1[0] + h0.y*w1[1] + h0.z*w1[2] + h0.w*w1[3]
             + h1.x*w1[4] + h1.y*w1[5] + h1.z*w1[6] + h1.w*w1[7];
    float v2 = h0.x*w2[0] + h0.y*w2[1] + h0.z*w2[2] + h0.w*w2[3]
             + h1.x*w2[4] + h1.y*w2[5] + h1.z*w2[6] + h1.w*w2[7];
    #pragma unroll
    for (int off = 32; off >= 1; off >>= 1) {
        v1 += __shfl_xor(v1, off, 64);
        v2 += __shfl_xor(v2, off, 64);
    }
    if (ln == 0) { s_src[i] = v1; s_dst[i] = v2; }
}

// ---------------------------------------------------------------------------
// K1: Wh = h @ W^T (fp32) -> whf bf16 in MFMA-B-fragment-major layout.
// chunk c = (j>>5)*16 + (n>>4); within: lane = (n&15) + ((j>>3)&3)*16,
// element = lane*8 + (j&7).   grid (4 colblk, 128 rowblk), 256 thr, 4x4/thr.
// ---------------------------------------------------------------------------
__global__ __launch_bounds__(256) void k1_wh_pack(
    const float* __restrict__ h, const float* __restrict__ W,
    uint16_t* __restrict__ whf)
{
    const int n0 = blockIdx.x * 64, i0 = blockIdx.y * 64;
    const int t  = threadIdx.x;
    const int tn = t & 15, tm = t >> 4;

    __shared__ float As[32][65];
    __shared__ float Bs[32][65];

    float acc[4][4];
    #pragma unroll
    for (int i = 0; i < 4; i++)
        #pragma unroll
        for (int j = 0; j < 4; j++) acc[i][j] = 0.f;

    for (int k0 = 0; k0 < IN_F; k0 += 32) {
        __syncthreads();
        #pragma unroll
        for (int q = 0; q < 2; q++) {
            int u   = q * 256 + t;
            int row = u >> 3;
            int kf  = (u & 7) * 4;
            float4 va = *(const float4*)&h[(size_t)(i0 + row) * IN_F + k0 + kf];
            As[kf + 0][row] = va.x; As[kf + 1][row] = va.y;
            As[kf + 2][row] = va.z; As[kf + 3][row] = va.w;
            float4 vb = *(const float4*)&W[(size_t)(n0 + row) * IN_F + k0 + kf];
            Bs[kf + 0][row] = vb.x; Bs[kf + 1][row] = vb.y;
            Bs[kf + 2][row] = vb.z; Bs[kf + 3][row] = vb.w;
        }
        __syncthreads();
        #pragma unroll
        for (int kk = 0; kk < 32; kk++) {
            float a[4], b[4];
            *(float4*)a = *(const float4*)&As[kk][tm * 4];
            *(float4*)b = *(const float4*)&Bs[kk][tn * 4];
            #pragma unroll
            for (int i = 0; i < 4; i++)
                #pragma unroll
                for (int j = 0; j < 4; j++) acc[i][j] = fmaf(a[i], b[j], acc[i][j]);
        }
    }

    #pragma unroll
    for (int ii = 0; ii < 4; ii++) {
        int gr = i0 + tm * 4 + ii;
        int ck = gr >> 5;
        int lr = (gr >> 3) & 3;
        int jj = gr & 7;
        #pragma unroll
        for (int jn = 0; jn < 4; jn++) {
            int gc   = n0 + tn * 4 + jn;
            int c    = ck * 16 + (gc >> 4);
            int lane = (gc & 15) + lr * 16;
            whf[(size_t)c * 512 + lane * 8 + jj] = (uint16_t)f32_to_bf16(acc[ii][jn]);
        }
    }
}

// ---------------------------------------------------------------------------
// K2: adjacency -> phase-interleaved bitmask + softmax denominators l[i].
// mask layout: word (i, jb, ph) bit b  <->  adj[i][jb*256 + b*4 + ph] > 0.
// Block = 1 row, 256 thr, float4 loads (1KB/wave/instr).
// ---------------------------------------------------------------------------
__global__ __launch_bounds__(256) void k2_mask_l(
    const float* __restrict__ adj, const float* __restrict__ s_src,
    const float* __restrict__ s_dst, uint64_t* __restrict__ mask,
    float* __restrict__ l_out)
{
    const int i = blockIdx.x;
    const int t = threadIdx.x, w = t >> 6, ln = t & 63;
    const float si = s_src[i];
    const float4* rowv = (const float4*)(adj + (size_t)i * N_NODES);
    const float4* sdv  = (const float4*)s_dst;
    float acc = 0.f;
    #pragma unroll 2
    for (int it = 0; it < 8; it++) {
        int jb = it * 4 + w;          // 256-j block, 0..31
        int v4 = jb * 64 + ln;
        float4 a  = rowv[v4];
        float4 sd = sdv[v4];
        uint64_t b0 = __ballot(a.x > 0.f);
        uint64_t b1 = __ballot(a.y > 0.f);
        uint64_t b2 = __ballot(a.z > 0.f);
        uint64_t b3 = __ballot(a.w > 0.f);
        if (ln == 0) {
            uint64_t* mw = mask + (size_t)i * 128 + jb * 4;
            mw[0] = b0; mw[1] = b1; mw[2] = b2; mw[3] = b3;
        }
        float x, e;
        x = si + sd.x; e = fmaxf(x, ALPHA * x); if (a.x > 0.f) acc += __expf(e);
        x = si + sd.y; e = fmaxf(x, ALPHA * x); if (a.y > 0.f) acc += __expf(e);
        x = si + sd.z; e = fmaxf(x, ALPHA * x); if (a.z > 0.f) acc += __expf(e);
        x = si + sd.w; e = fmaxf(x, ALPHA * x); if (a.w > 0.f) acc += __expf(e);
    }
    #pragma unroll
    for (int off = 32; off >= 1; off >>= 1) acc += __shfl_xor(acc, off, 64);
    __shared__ float red[4];
    if (ln == 0) red[w] = acc;
    __syncthreads();
    if (t == 0) l_out[i] = (red[0] + red[1]) + (red[2] + red[3]);
}

// ---------------------------------------------------------------------------
// K3: fused attention-write + (attention @ Wh) bf16 MFMA GEMM.
// grid (256 rb, 4 jc), 256 thr. Block: 32 rows x 2048 j, 32 iters of BK=64.
// A-fragments computed IN REGISTERS (each wave computes the frags it consumes;
// nh duplicates exp work, only nh==0 stores att). WhF staged via
// global_load_lds width=16 (overlaps the exp/att-store phase).
// ---------------------------------------------------------------------------
__global__ __launch_bounds__(256) void k3_att_gemm(
    const uint64_t* __restrict__ mask, const float* __restrict__ s_src,
    const float* __restrict__ s_dst, const float* __restrict__ l_in,
    const uint16_t* __restrict__ whf, float* __restrict__ att_out,
    float* __restrict__ partial)
{
    const int rb = blockIdx.x, jc = blockIdx.y;
    const int i0 = rb * 32, jbase = jc * 2048;
    const int t = threadIdx.x, w = t >> 6, ln = t & 63;
    const int mh = w & 1, nh = w >> 1;

    __shared__ uint16_t whf_lds[16384];     // 32 KB: 2 ksteps x 16 ntiles
    __shared__ uint64_t mw[2][32][4];
    __shared__ float    sd[2][64];
    __shared__ float    ssrc[32], invl[32];

    if (t < 32) { ssrc[t] = s_src[i0 + t]; invl[t] = 1.0f / l_in[i0 + t]; }
    if (t < 64) sd[0][t] = s_dst[jbase + t];
    if (t >= 64 && t < 192) {
        int r = (t - 64) >> 2, ph = t & 3;
        mw[0][r][ph] = mask[(size_t)(i0 + r) * 128 + (jbase >> 8) * 4 + ph];
    }

    f32x4 acc[8];
    #pragma unroll
    for (int b = 0; b < 8; b++) acc[b] = (f32x4){0.f, 0.f, 0.f, 0.f};

    const int m   = mh * 16 + (ln & 15);    // row within block, 0..31
    const int kof = (ln >> 4) * 8;          // 0,8,16,24

    int cur = 0;
    for (int it = 0; it < 32; it++) {
        const int j0 = jbase + it * 64;
        __syncthreads();   // mw/sd[cur] visible; prev MFMA done with whf_lds

        // async stage WhF tile (32 KB, 8 wave-instrs per wave)
        const uint16_t* src = whf + (size_t)(j0 >> 5) * 8192;
        #pragma unroll
        for (int q = 0; q < 8; q++) {
            int c = w * 8 + q;
            async_copy16(src + (size_t)c * 512 + ln * 8, whf_lds + c * 512);
        }

        // compute this wave's A-fragments in registers
        uint64_t mwv[4];
        #pragma unroll
        for (int ph = 0; ph < 4; ph++) mwv[ph] = mw[cur][m][ph];
        float sim = ssrc[m], il = invl[m];
        int bbase = ((it & 3) << 4) + (kof >> 2);
        float p[2][8];
        #pragma unroll
        for (int ks = 0; ks < 2; ks++) {
            #pragma unroll
            for (int jj = 0; jj < 8; jj++) {
                float x  = sim + sd[cur][ks * 32 + kof + jj];
                float e  = fmaxf(x, ALPHA * x);
                float pe = __expf(e) * il;
                int bidx = bbase + ks * 8 + (jj >> 2);
                p[ks][jj] = ((mwv[jj & 3] >> bidx) & 1ull) ? pe : 0.f;
            }
        }

        // att store (nontemporal; only nh==0 waves to avoid duplicates)
        if (nh == 0) {
            float* go = att_out + (size_t)(i0 + m) * N_NODES + j0 + kof;
            __builtin_nontemporal_store(*(f32x4*)&p[0][0], (f32x4*)go);
            __builtin_nontemporal_store(*(f32x4*)&p[0][4], (f32x4*)(go + 4));
            __builtin_nontemporal_store(*(f32x4*)&p[1][0], (f32x4*)(go + 32));
            __builtin_nontemporal_store(*(f32x4*)&p[1][4], (f32x4*)(go + 36));
        }

        // pack A-fragments to bf16
        bf16x8 af[2];
        #pragma unroll
        for (int ks = 0; ks < 2; ks++) {
            union { bf16x8 v; uint32_t u[4]; } pk;
            #pragma unroll
            for (int q = 0; q < 4; q++)
                pk.u[q] = f32_to_bf16(p[ks][2 * q]) | (f32_to_bf16(p[ks][2 * q + 1]) << 16);
            af[ks] = pk.v;
        }

        // preload next iter's mask words + s_dst
        if (it < 31) {
            int jn = j0 + 64;
            if (t < 64) sd[cur ^ 1][t] = s_dst[jn + t];
            else if (t < 192) {
                int r = (t - 64) >> 2, ph = t & 3;
                mw[cur ^ 1][r][ph] = mask[(size_t)(i0 + r) * 128 + (jn >> 8) * 4 + ph];
            }
        }
        __syncthreads();   // whf_lds ready (barrier drains vmcnt), nxt bufs written

        #pragma unroll
        for (int ks = 0; ks < 2; ks++) {
            #pragma unroll
            for (int nl = 0; nl < 8; nl++) {
                int nt = nh * 8 + nl;
                bf16x8 bfr = *(const bf16x8*)(whf_lds + (size_t)(ks * 16 + nt) * 512 + ln * 8);
                acc[nl] = __builtin_amdgcn_mfma_f32_16x16x32_bf16(af[ks], bfr, acc[nl], 0, 0, 0);
            }
        }
        cur ^= 1;
    }

    // epilogue: partial[jc][row][col]; C/D: col=lane&15, row=(lane>>4)*4+reg
    float* pbase = partial + (size_t)jc * ((size_t)N_NODES * OUT_F);
    int gr0 = i0 + mh * 16 + (ln >> 4) * 4;
    #pragma unroll
    for (int nl = 0; nl < 8; nl++) {
        int gc = nh * 128 + nl * 16 + (ln & 15);
        #pragma unroll
        for (int r = 0; r < 4; r++)
            pbase[(size_t)(gr0 + r) * OUT_F + gc] = acc[nl][r];
    }
}

// ---------------------------------------------------------------------------
// K4: h_prime = sum of 4 split-K partials
// ---------------------------------------------------------------------------
__global__ __launch_bounds__(256) void k4_reduce(
    const float* __restrict__ partial, float* __restrict__ hp)
{
    const size_t S = (size_t)N_NODES * OUT_F;
    int idx = (blockIdx.x * 256 + threadIdx.x) * 4;
    float4 a = *(const float4*)(partial + idx);
    float4 b = *(const float4*)(partial + S + idx);
    float4 c = *(const float4*)(partial + 2 * S + idx);
    float4 d = *(const float4*)(partial + 3 * S + idx);
    float4 o;
    o.x = (a.x + b.x) + (c.x + d.x);
    o.y = (a.y + b.y) + (c.y + d.y);
    o.z = (a.z + b.z) + (c.z + d.z);
    o.w = (a.w + b.w) + (c.w + d.w);
    *(float4*)(hp + idx) = o;
}

extern "C" void kernel_launch(void* const* d_in, const int* in_sizes, int n_in,
                              void* d_out, int out_size, void* d_ws, size_t ws_size,
                              hipStream_t stream) {
    (void)in_sizes; (void)n_in; (void)out_size; (void)ws_size;
    const float* h     = (const float*)d_in[0];
    const float* adj   = (const float*)d_in[1];
    const float* W     = (const float*)d_in[2];
    const float* a_vec = (const float*)d_in[3];

    char* ws = (char*)d_ws;
    uint16_t* whf  = (uint16_t*)(ws);                          // 4 MB
    uint64_t* mask = (uint64_t*)(ws + ((size_t)4 << 20));      // 8 MB
    float* partial = (float*)(ws + ((size_t)12 << 20));        // 32 MB
    float* w12     = (float*)(ws + ((size_t)44 << 20));        // 4 KB
    float* s_src   = (float*)(ws + ((size_t)44 << 20) + 16384);
    float* s_dst   = (float*)(ws + ((size_t)44 << 20) + 16384 + 32768);
    float* l_buf   = (float*)(ws + ((size_t)44 << 20) + 16384 + 65536);

    float* hp  = (float*)d_out;
    float* att = hp + (size_t)N_NODES * OUT_F;

    hipMemsetAsync(w12, 0, 4096, stream);
    k0_wvec<<<32, 256, 0, stream>>>(W, a_vec, w12);
    ks_svec<<<2048, 256, 0, stream>>>(h, w12, s_src, s_dst);
    k1_wh_pack<<<dim3(4, 128), 256, 0, stream>>>(h, W, whf);
    k2_mask_l<<<8192, 256, 0, stream>>>(adj, s_src, s_dst, mask, l_buf);
    k3_att_gemm<<<dim3(256, 4), 256, 0, stream>>>(mask, s_src, s_dst, l_buf, whf, att, partial);
    k4_reduce<<<2048, 256, 0, stream>>>(partial, hp);
}